// Round 3
// baseline (6076.300 us; speedup 1.0000x reference)
//
#include <hip/hip_runtime.h>
#include <math.h>

#define N 64

__device__ __forceinline__ float shfl_xor_f(float v, int m) {
    return __shfl_xor(v, m, 64);
}
__device__ __forceinline__ float shfl_f(float v, int src) {
    return __shfl(v, src, 64);
}

// In-register 64x64 butterfly transpose: lane j holds a[] = column j on entry,
// row j on exit.
__device__ __forceinline__ void transpose64(float (&a)[N], int lane) {
#pragma unroll
    for (int b = 1; b < N; b <<= 1) {
        bool upper = (lane & b) != 0;
#pragma unroll
        for (int i = 0; i < N; ++i) {
            if ((i & b) == 0) {
                float lo = a[i], hi = a[i | b];
                float send = upper ? lo : hi;
                float recv = shfl_xor_f(send, b);
                a[i]     = upper ? recv : lo;
                a[i | b] = upper ? hi : recv;
            }
        }
    }
}

__device__ __forceinline__ float norm2_64(const float (&g)[N]) {
    float a0 = 0.f, a1 = 0.f, a2 = 0.f, a3 = 0.f;
#pragma unroll
    for (int i = 0; i < N; i += 4) {
        a0 = fmaf(g[i + 0], g[i + 0], a0);
        a1 = fmaf(g[i + 1], g[i + 1], a1);
        a2 = fmaf(g[i + 2], g[i + 2], a2);
        a3 = fmaf(g[i + 3], g[i + 3], a3);
    }
    return (a0 + a1) + (a2 + a3);
}

// One-sided Jacobi on columns-in-registers. Lane `lane` owns column g[].
// Converges to g_k = lambda_k * q_k. Returns final exact column norm^2
// (= lambda^2). Early-exits when all pair rotations in a sweep are below
// tolerance (wave-uniform via __any).
__device__ __forceinline__ float jacobi_onesided(float (&g)[N], int lane, int max_sweeps) {
    float d = 0.0f;
    for (int s = 0; s < max_sweeps; ++s) {
        d = norm2_64(g);   // exact at sweep start; maintained within sweep
        int anybad = 0;
        for (int m = 1; m < N; ++m) {
            float t[N];
#pragma unroll
            for (int i = 0; i < N; ++i) t[i] = shfl_xor_f(g[i], m);
            // o = <g_self, g_partner>; bitwise identical on both lanes of a pair
            float o0 = 0.f, o1 = 0.f, o2 = 0.f, o3 = 0.f;
#pragma unroll
            for (int i = 0; i < N; i += 4) {
                o0 = fmaf(g[i + 0], t[i + 0], o0);
                o1 = fmaf(g[i + 1], t[i + 1], o1);
                o2 = fmaf(g[i + 2], t[i + 2], o2);
                o3 = fmaf(g[i + 3], t[i + 3], o3);
            }
            float o = (o0 + o1) + (o2 + o3);
            float doth = shfl_xor_f(d, m);
            bool is_lo = lane < (lane ^ m);
            float dp = is_lo ? d : doth;
            float dq = is_lo ? doth : d;
            anybad |= (o * o > 1e-11f * dp * dq) ? 1 : 0;
            bool skip = (o * o) <= (1e-24f * dp * dq);
            float osafe = skip ? 1.0f : o;
            // zero the implicit Gram off-diagonal: small-|t| root of
            // t^2 - 2*theta*t - 1 = 0, theta = (dq-dp)/(2o)
            float theta = (dq - dp) / (2.0f * osafe);
            float tt = -copysignf(1.0f, theta) /
                       (fabsf(theta) + sqrtf(fmaf(theta, theta, 1.0f)));
            float c = rsqrtf(fmaf(tt, tt, 1.0f));
            float sv = tt * c;
            c = skip ? 1.0f : c;
            sv = skip ? 0.0f : sv;
            float c2 = c * c, s2 = sv * sv, cso = 2.0f * c * sv * o;
            d = is_lo ? fmaf(c2, dp, fmaf(s2, dq, cso))
                      : fmaf(s2, dp, fmaf(c2, dq, -cso));
            d = fmaxf(d, 1e-30f);
            float ss = is_lo ? sv : -sv;
#pragma unroll
            for (int i = 0; i < N; ++i) g[i] = fmaf(ss, t[i], c * g[i]);
        }
        if (!__any(anybad)) break;   // wave-uniform
    }
    return norm2_64(g);
}

// out = sum_k coef_k * g_k * g_k^T, written column `lane` (coalesced stores).
// Lane k holds coef_k = f(lambda_k)/d_k so coef_k*g_k[i]*g_k[j] = f_k*q_k[i]*q_k[j].
__device__ __forceinline__ void spectral_recon_store(float (&g)[N], float coef,
                                                     int lane, float* __restrict__ outp) {
    float rowg[N];
#pragma unroll
    for (int i = 0; i < N; ++i) rowg[i] = g[i];
    transpose64(rowg, lane);          // rowg[k] = g_k[lane]
#pragma unroll
    for (int k = 0; k < N; ++k) rowg[k] *= shfl_f(coef, k);
#pragma unroll
    for (int base = 0; base < N; base += 16) {
        float acc[16];
#pragma unroll
        for (int i = 0; i < 16; ++i) acc[i] = 0.f;
#pragma unroll
        for (int k = 0; k < N; ++k) {
            float w = rowg[k];
#pragma unroll
            for (int i = 0; i < 16; ++i)
                acc[i] = fmaf(shfl_f(g[base + i], k), w, acc[i]);
        }
#pragma unroll
        for (int i = 0; i < 16; ++i)
            outp[(base + i) * N + lane] = acc[i];
    }
}

// Kernel A: R_c = ((1-psi) W_c + psi I)^{-1/2}, one wave per channel (C=4).
// launch_bounds(64,1): min 1 wave/EU -> allocator free to hold the true live
// set (~170 VGPRs) instead of shuttling t[]/rowg[] through AGPRs or scratch.
__global__ __launch_bounds__(64, 1) void prep_R(const float* __restrict__ wgt,
                                                float* __restrict__ Rws) {
    int c = blockIdx.x;
    int lane = threadIdx.x;
    const float* W = wgt + c * N * N;
    float g[N];
#pragma unroll
    for (int i = 0; i < N; ++i)
        g[i] = (1.0f - 0.001f) * W[i * N + lane] + ((i == lane) ? 0.001f : 0.0f);
    float d = jacobi_onesided(g, lane, 15);
    // f(lambda) = lambda^{-1/2}; lambda = sqrt(d); coef = f/d = d^{-5/4}
    float coef = sqrtf(rsqrtf(d)) / d;
    spectral_recon_store(g, coef, lane, Rws + c * N * N);
}

// Kernel B: per (b,c): M = R_c Theta_b R_c -> symmetrize -> recondition -> log.
__global__ __launch_bounds__(64, 1) void tangent_log(const float* __restrict__ inp,
                                                     const float* __restrict__ Rws,
                                                     float* __restrict__ out) {
    int bid = blockIdx.x;
    int b = bid >> 2;
    int c = bid & 3;
    int lane = threadIdx.x;
    const float* Th = inp + (size_t)b * (N * N);
    const float* Rc = Rws + c * (N * N);

    // r = column `lane` of R (coalesced)
    float r[N];
#pragma unroll
    for (int k = 0; k < N; ++k) r[k] = Rc[k * N + lane];

    // u = Theta * r  (Theta symmetric; wave-uniform row addresses -> s_load)
    float u[N];
#pragma unroll
    for (int i = 0; i < N; ++i) u[i] = 0.f;
#pragma unroll
    for (int k = 0; k < N; ++k) {
        const float4* row = (const float4*)(Th + k * N);
        float rk = r[k];
#pragma unroll
        for (int q = 0; q < N / 4; ++q) {
            float4 v = row[q];
            u[4 * q + 0] = fmaf(v.x, rk, u[4 * q + 0]);
            u[4 * q + 1] = fmaf(v.y, rk, u[4 * q + 1]);
            u[4 * q + 2] = fmaf(v.z, rk, u[4 * q + 2]);
            u[4 * q + 3] = fmaf(v.w, rk, u[4 * q + 3]);
        }
    }

    // g = R * u (R symmetric)
    float g[N];
#pragma unroll
    for (int i = 0; i < N; ++i) g[i] = 0.f;
#pragma unroll
    for (int k = 0; k < N; ++k) {
        const float4* row = (const float4*)(Rc + k * N);
        float uk = u[k];
#pragma unroll
        for (int q = 0; q < N / 4; ++q) {
            float4 v = row[q];
            g[4 * q + 0] = fmaf(v.x, uk, g[4 * q + 0]);
            g[4 * q + 1] = fmaf(v.y, uk, g[4 * q + 1]);
            g[4 * q + 2] = fmaf(v.z, uk, g[4 * q + 2]);
            g[4 * q + 3] = fmaf(v.w, uk, g[4 * q + 3]);
        }
    }

    // symmetrize: g <- 0.5*(M + M^T) column `lane`  (reference resymmetrizes)
    {
        float tr[N];
#pragma unroll
        for (int i = 0; i < N; ++i) tr[i] = g[i];
        transpose64(tr, lane);        // tr[i] = M[lane][i]
#pragma unroll
        for (int i = 0; i < N; ++i) g[i] = 0.5f * (g[i] + tr[i]);
    }

    // convex recondition with identity
#pragma unroll
    for (int i = 0; i < N; ++i)
        g[i] = (1.0f - 0.001f) * g[i] + ((i == lane) ? 0.001f : 0.0f);

    float d = jacobi_onesided(g, lane, 15);
    // f(lambda) = log(lambda) = 0.5*log(d); coef = f/d
    float coef = 0.5f * logf(d) / d;
    spectral_recon_store(g, coef, lane, out + (size_t)bid * (N * N));
}

extern "C" void kernel_launch(void* const* d_in, const int* in_sizes, int n_in,
                              void* d_out, int out_size, void* d_ws, size_t ws_size,
                              hipStream_t stream) {
    const float* inp = (const float*)d_in[0];   // [B,64,64] f32
    const float* wgt = (const float*)d_in[1];   // [C,64,64] f32
    float* out = (float*)d_out;                 // [B,C,64,64] f32
    float* Rws = (float*)d_ws;                  // C*64*64 floats scratch

    int B = in_sizes[0] / (N * N);
    int C = in_sizes[1] / (N * N);

    hipLaunchKernelGGL(prep_R, dim3(C), dim3(64), 0, stream, wgt, Rws);
    hipLaunchKernelGGL(tangent_log, dim3(B * C), dim3(64), 0, stream, inp, Rws, out);
}

// Round 4
// 5501.477 us; speedup vs baseline: 1.1045x; 1.1045x over previous
//
#include <hip/hip_runtime.h>
#include <math.h>

#define N 64
typedef float f32x2 __attribute__((ext_vector_type(2)));

__device__ __forceinline__ float bperm(int byteaddr, float v) {
    return __int_as_float(__builtin_amdgcn_ds_bpermute(byteaddr, __float_as_int(v)));
}
// row accessors into f32x2-packed column storage (i must be compile-time)
__device__ __forceinline__ float getrow(const f32x2 (&a)[N / 2], int i) {
    return (i & 1) ? a[i >> 1].y : a[i >> 1].x;
}
__device__ __forceinline__ void setrow(f32x2 (&a)[N / 2], int i, float v) {
    if (i & 1) a[i >> 1].y = v; else a[i >> 1].x = v;
}

// In-register 64x64 butterfly transpose: lane j holds column j on entry, row j on exit.
__device__ __forceinline__ void transpose64(f32x2 (&a)[N / 2], int lane) {
#pragma unroll
    for (int b = 1; b < N; b <<= 1) {
        bool upper = (lane & b) != 0;
#pragma unroll
        for (int i = 0; i < N; ++i) {
            if ((i & b) == 0) {
                float lo = getrow(a, i), hi = getrow(a, i | b);
                float send = upper ? lo : hi;
                float recv = __shfl_xor(send, b, 64);
                setrow(a, i, upper ? recv : lo);
                setrow(a, i | b, upper ? hi : recv);
            }
        }
    }
}

__device__ __forceinline__ float norm2_64(const f32x2 (&g)[N / 2]) {
    f32x2 a = {0.f, 0.f}, b = {0.f, 0.f};
#pragma unroll
    for (int i = 0; i < N / 2; i += 2) {
        a = g[i] * g[i] + a;
        b = g[i + 1] * g[i + 1] + b;
    }
    f32x2 s = a + b;
    return s.x + s.y;
}

// One-sided Jacobi, columns-in-registers (f32x2-packed rows). Lane owns column.
// Converges to g_k = lambda_k * q_k. Returns final column norm^2 (= lambda^2).
__device__ __forceinline__ float jacobi_onesided(f32x2 (&g)[N / 2], int lane, int max_sweeps) {
#pragma clang loop unroll(disable)
    for (int s = 0; s < max_sweeps; ++s) {
        float d = norm2_64(g);  // exact at sweep start; maintained within sweep
        int anybad = 0;
#pragma clang loop unroll(disable)
        for (int m = 1; m < N; ++m) {
            int paddr = (lane ^ m) << 2;
            f32x2 t[N / 2];
#pragma unroll
            for (int i = 0; i < N / 2; ++i) {
                t[i].x = bperm(paddr, g[i].x);
                t[i].y = bperm(paddr, g[i].y);
            }
            f32x2 oa = {0.f, 0.f}, ob = {0.f, 0.f};
#pragma unroll
            for (int i = 0; i < N / 2; i += 2) {
                oa = g[i] * t[i] + oa;
                ob = g[i + 1] * t[i + 1] + ob;
            }
            f32x2 os = oa + ob;
            float o = os.x + os.y;
            float doth = bperm(paddr, d);
            bool is_lo = lane < (lane ^ m);
            float dp = is_lo ? d : doth;
            float dq = is_lo ? doth : d;
            anybad |= (o * o > 1e-11f * dp * dq) ? 1 : 0;
            bool skip = (o * o) <= (1e-24f * dp * dq);
            float osafe = skip ? 1.0f : o;
            // small-|t| root of t^2 + 2*theta*t - 1 = 0, theta = (dq-dp)/(2o)
            float theta = (dq - dp) / (2.0f * osafe);
            float tt = -copysignf(1.0f, theta) /
                       (fabsf(theta) + sqrtf(fmaf(theta, theta, 1.0f)));
            float c = rsqrtf(fmaf(tt, tt, 1.0f));
            float sv = tt * c;
            c = skip ? 1.0f : c;
            sv = skip ? 0.0f : sv;
            float c2 = c * c, s2 = sv * sv, cso = 2.0f * c * sv * o;
            d = is_lo ? fmaf(c2, dp, fmaf(s2, dq, cso))
                      : fmaf(s2, dp, fmaf(c2, dq, -cso));
            d = fmaxf(d, 1e-30f);
            float ss = is_lo ? sv : -sv;
            f32x2 cv = {c, c}, sv2 = {ss, ss};
#pragma unroll
            for (int i = 0; i < N / 2; ++i)
                g[i] = sv2 * t[i] + cv * g[i];
        }
        if (!__any(anybad)) break;  // wave-uniform
    }
    return norm2_64(g);
}

// out = sum_k coef_k * g_k * g_k^T, written column `lane` (coalesced stores).
__device__ __forceinline__ void spectral_recon_store(f32x2 (&g)[N / 2], float coef,
                                                     int lane, float* __restrict__ outp) {
    f32x2 rowg[N / 2];
#pragma unroll
    for (int i = 0; i < N / 2; ++i) rowg[i] = g[i];
    transpose64(rowg, lane);  // row k of rowg = g_k[lane]
#pragma unroll
    for (int k = 0; k < N; ++k) {
        float ck = bperm(k << 2, coef);  // broadcast coef_k from lane k
        setrow(rowg, k, getrow(rowg, k) * ck);
    }
#pragma unroll
    for (int base = 0; base < N; base += 16) {
        f32x2 acc[8];
#pragma unroll
        for (int j = 0; j < 8; ++j) { acc[j].x = 0.f; acc[j].y = 0.f; }
#pragma unroll
        for (int k = 0; k < N; ++k) {
            float w = getrow(rowg, k);
            f32x2 wv = {w, w};
            int kaddr = k << 2;
#pragma unroll
            for (int j = 0; j < 8; ++j) {
                f32x2 mv;
                mv.x = bperm(kaddr, g[base / 2 + j].x);
                mv.y = bperm(kaddr, g[base / 2 + j].y);
                acc[j] = mv * wv + acc[j];
            }
        }
#pragma unroll
        for (int j = 0; j < 8; ++j) {
            outp[(base + 2 * j) * N + lane]     = acc[j].x;
            outp[(base + 2 * j + 1) * N + lane] = acc[j].y;
        }
    }
}

// Kernel A: R_c = ((1-psi) W_c + psi I)^{-1/2}, one wave per channel (C=4).
__global__ __launch_bounds__(64) __attribute__((amdgpu_waves_per_eu(1)))
void prep_R(const float* __restrict__ wgt, float* __restrict__ Rws) {
    int c = blockIdx.x;
    int lane = threadIdx.x;
    const float* W = wgt + c * N * N;
    f32x2 g[N / 2];
#pragma unroll
    for (int i = 0; i < N; ++i)
        setrow(g, i, 0.999f * W[i * N + lane] + ((i == lane) ? 0.001f : 0.0f));
    float d = jacobi_onesided(g, lane, 15);
    // f(lambda) = lambda^{-1/2}; lambda = sqrt(d); coef = f/d = d^{-5/4}
    float coef = sqrtf(rsqrtf(d)) / d;
    spectral_recon_store(g, coef, lane, Rws + c * N * N);
}

// Kernel B: per (b,c): M = R_c Theta_b R_c -> symmetrize -> recondition -> log.
__global__ __launch_bounds__(64) __attribute__((amdgpu_waves_per_eu(1)))
void tangent_log(const float* __restrict__ inp, const float* __restrict__ Rws,
                 float* __restrict__ out) {
    int bid = blockIdx.x;
    int b = bid >> 2;
    int c = bid & 3;
    int lane = threadIdx.x;
    const float* Th = inp + (size_t)b * (N * N);
    const float* Rc = Rws + c * (N * N);

    // r = column `lane` of R (coalesced)
    f32x2 r[N / 2];
#pragma unroll
    for (int k = 0; k < N; ++k) setrow(r, k, Rc[k * N + lane]);

    // u = Theta * r (Theta symmetric; broadcast float4 row loads)
    f32x2 u[N / 2];
#pragma unroll
    for (int i = 0; i < N / 2; ++i) { u[i].x = 0.f; u[i].y = 0.f; }
#pragma unroll
    for (int k = 0; k < N; ++k) {
        const float4* row = (const float4*)(Th + k * N);
        float rk = getrow(r, k);
        f32x2 rv = {rk, rk};
#pragma unroll
        for (int q = 0; q < N / 4; ++q) {
            float4 v = row[q];
            f32x2 v0 = {v.x, v.y}, v1 = {v.z, v.w};
            u[2 * q]     = v0 * rv + u[2 * q];
            u[2 * q + 1] = v1 * rv + u[2 * q + 1];
        }
    }

    // g = R * u (R symmetric)
    f32x2 g[N / 2];
#pragma unroll
    for (int i = 0; i < N / 2; ++i) { g[i].x = 0.f; g[i].y = 0.f; }
#pragma unroll
    for (int k = 0; k < N; ++k) {
        const float4* row = (const float4*)(Rc + k * N);
        float uk = getrow(u, k);
        f32x2 uv = {uk, uk};
#pragma unroll
        for (int q = 0; q < N / 4; ++q) {
            float4 v = row[q];
            f32x2 v0 = {v.x, v.y}, v1 = {v.z, v.w};
            g[2 * q]     = v0 * uv + g[2 * q];
            g[2 * q + 1] = v1 * uv + g[2 * q + 1];
        }
    }

    // symmetrize: g <- 0.5*(M + M^T) column `lane`  (reference resymmetrizes)
    {
        f32x2 tr[N / 2];
#pragma unroll
        for (int i = 0; i < N / 2; ++i) tr[i] = g[i];
        transpose64(tr, lane);
        f32x2 h = {0.5f, 0.5f};
#pragma unroll
        for (int i = 0; i < N / 2; ++i) g[i] = h * (g[i] + tr[i]);
    }

    // convex recondition with identity
#pragma unroll
    for (int i = 0; i < N; ++i)
        setrow(g, i, 0.999f * getrow(g, i) + ((i == lane) ? 0.001f : 0.0f));

    float d = jacobi_onesided(g, lane, 15);
    // f(lambda) = log(lambda) = 0.5*log(d); coef = f/d
    float coef = 0.5f * logf(d) / d;
    spectral_recon_store(g, coef, lane, out + (size_t)bid * (N * N));
}

extern "C" void kernel_launch(void* const* d_in, const int* in_sizes, int n_in,
                              void* d_out, int out_size, void* d_ws, size_t ws_size,
                              hipStream_t stream) {
    const float* inp = (const float*)d_in[0];   // [B,64,64] f32
    const float* wgt = (const float*)d_in[1];   // [C,64,64] f32
    float* out = (float*)d_out;                 // [B,C,64,64] f32
    float* Rws = (float*)d_ws;                  // C*64*64 floats scratch

    int B = in_sizes[0] / (N * N);
    int C = in_sizes[1] / (N * N);

    hipLaunchKernelGGL(prep_R, dim3(C), dim3(64), 0, stream, wgt, Rws);
    hipLaunchKernelGGL(tangent_log, dim3(B * C), dim3(64), 0, stream, inp, Rws, out);
}